// Round 3
// baseline (822.340 us; speedup 1.0000x reference)
//
#include <hip/hip_runtime.h>
#include <cstdint>
#include <cstddef>

// Sizes (fixed): B=512, N=200, F=32, E=H=128, L=2, 4H=512
#define LEAK 0.01f

typedef _Float16 f16;
typedef __attribute__((ext_vector_type(4))) _Float16 f16x4;
typedef __attribute__((ext_vector_type(8))) _Float16 f16x8;
typedef __attribute__((ext_vector_type(4))) float f32x4;

static __device__ __forceinline__ float sigm(float x) {
  return __builtin_amdgcn_rcpf(1.0f + __expf(-x));
}
static __device__ __forceinline__ float tanh_f(float x) {
  // overflow-free: tanh(x) = sign(x) * (1-t)/(1+t), t = exp(-2|x|) <= 1
  float t = __expf(-2.0f * __builtin_fabsf(x));
  float r = (1.0f - t) * __builtin_amdgcn_rcpf(1.0f + t);
  return __builtin_copysignf(r, x);
}
static __device__ __forceinline__ unsigned short f2bf(float f) {
  unsigned u = __builtin_bit_cast(unsigned, f);
  u += 0x7fffu + ((u >> 16) & 1u);
  return (unsigned short)(u >> 16);
}
static __device__ __forceinline__ float bf2f(unsigned short h) {
  return __builtin_bit_cast(float, (unsigned)h << 16);
}
static __device__ __forceinline__ f16x8 pack8(float4 a, float4 b) {
  f16x8 r;
  r[0] = (f16)a.x; r[1] = (f16)a.y; r[2] = (f16)a.z; r[3] = (f16)a.w;
  r[4] = (f16)b.x; r[5] = (f16)b.y; r[6] = (f16)b.z; r[7] = (f16)b.w;
  return r;
}
#define MFMA16(a, b, c) __builtin_amdgcn_mfma_f32_16x16x32_f16((a), (b), (c), 0, 0, 0)

// ---------------------------------------------------------------------------
// k_emb: e[t][b][j] = leaky_relu(x[b][t][:] . w_emb[j][:] + b_emb[j]), f16
// grid=200 (one WG per t), block=256; each thread handles 2 batch rows.
// ---------------------------------------------------------------------------
__global__ __launch_bounds__(256) void k_emb(
    const float* __restrict__ x, const float* __restrict__ wemb,
    const float* __restrict__ bemb, f16* __restrict__ e) {
  const int t = blockIdx.x, tid = threadIdx.x;
  __shared__ __align__(16) float wl[128 * 32];
  __shared__ float bl[128];
  for (int idx = tid; idx < 1024; idx += 256)
    ((float4*)wl)[idx] = ((const float4*)wemb)[idx];
  if (tid < 128) bl[tid] = bemb[tid];

  float xa[32], xb[32];
  const float* xpa = x + ((size_t)tid * 200 + t) * 32;
  const float* xpb = x + ((size_t)(tid + 256) * 200 + t) * 32;
#pragma unroll
  for (int k4 = 0; k4 < 8; ++k4) {
    float4 va = *(const float4*)(xpa + k4 * 4);
    float4 vb = *(const float4*)(xpb + k4 * 4);
    xa[k4 * 4 + 0] = va.x; xa[k4 * 4 + 1] = va.y; xa[k4 * 4 + 2] = va.z; xa[k4 * 4 + 3] = va.w;
    xb[k4 * 4 + 0] = vb.x; xb[k4 * 4 + 1] = vb.y; xb[k4 * 4 + 2] = vb.z; xb[k4 * 4 + 3] = vb.w;
  }
  __syncthreads();

  f16* ea = e + ((size_t)t * 512 + tid) * 128;
  f16* eb = e + ((size_t)t * 512 + tid + 256) * 128;
  for (int j8 = 0; j8 < 16; ++j8) {
    f16x8 oa, ob;
#pragma unroll
    for (int jj = 0; jj < 8; ++jj) {
      int j = j8 * 8 + jj;
      float aa = bl[j], ab = bl[j];
#pragma unroll
      for (int k4 = 0; k4 < 8; ++k4) {
        float4 wv = *(const float4*)&wl[j * 32 + k4 * 4];
        aa += xa[k4 * 4 + 0] * wv.x + xa[k4 * 4 + 1] * wv.y +
              xa[k4 * 4 + 2] * wv.z + xa[k4 * 4 + 3] * wv.w;
        ab += xb[k4 * 4 + 0] * wv.x + xb[k4 * 4 + 1] * wv.y +
              xb[k4 * 4 + 2] * wv.z + xb[k4 * 4 + 3] * wv.w;
      }
      oa[jj] = (f16)(aa >= 0.f ? aa : LEAK * aa);
      ob[jj] = (f16)(ab >= 0.f ? ab : LEAK * ab);
    }
    *(f16x8*)(ea + j8 * 8) = oa;
    *(f16x8*)(eb + j8 * 8) = ob;
  }
}

// ---------------------------------------------------------------------------
// k_xp: parallel x-projection GEMM for one layer / time chunk.
// xp[tl][bt][w][lane][G][r] (f16) = e[t][b] @ Wih^T + (bih+bhh), stored in
// the exact MFMA C-fragment layout k_rec consumes (32 B per lane per step).
// grid = CH*8 WGs, block=256 (4 waves). Wave pw owns gate block G=pw.
// Each WG processes 4 (tl,bt) pairs to amortize the weight-fragment load.
// ---------------------------------------------------------------------------
__global__ __launch_bounds__(256, 2) void k_xp(
    const f16* __restrict__ e, const float* __restrict__ wih,
    const float* __restrict__ bih, const float* __restrict__ bhh,
    f16* __restrict__ xp, int t0) {
  const int g = blockIdx.x, tid = threadIdx.x;
  const int pw = tid >> 6, lane = tid & 63, q = lane >> 4, l16 = lane & 15;

  f16x8 BW[8][4];
  float bias[8];
#pragma unroll
  for (int ct = 0; ct < 8; ++ct) {
    int n = pw * 128 + ct * 16 + l16;
    bias[ct] = bih[n] + bhh[n];
#pragma unroll
    for (int kc = 0; kc < 4; ++kc) {
      const float4* p = (const float4*)(wih + (size_t)n * 128 + kc * 32 + q * 8);
      BW[ct][kc] = pack8(p[0], p[1]);
    }
  }
#pragma unroll
  for (int i = 0; i < 4; ++i) {
    int idx = g * 4 + i;
    int tl = idx >> 5, bt = idx & 31;
    const f16* A = e + ((size_t)(t0 + tl) * 512 + bt * 16 + l16) * 128 + q * 8;
    f16x8 af[4];
#pragma unroll
    for (int kc = 0; kc < 4; ++kc) af[kc] = *(const f16x8*)(A + kc * 32);
    f16* dst = xp + ((size_t)tl * 32 + bt) * 8192;  // 8 waves * 64 lanes * 16
#pragma unroll
    for (int ct = 0; ct < 8; ++ct) {
      f32x4 acc = (f32x4){bias[ct], bias[ct], bias[ct], bias[ct]};
#pragma unroll
      for (int kc = 0; kc < 4; ++kc) acc = MFMA16(af[kc], BW[ct][kc], acc);
      f16x4 o;
      o[0] = (f16)acc[0]; o[1] = (f16)acc[1]; o[2] = (f16)acc[2]; o[3] = (f16)acc[3];
      *(f16x4*)(dst + ((size_t)ct * 64 + lane) * 16 + pw * 4) = o;
    }
  }
}

// ---------------------------------------------------------------------------
// k_rec: LSTM recurrence only (h @ Whh^T + precomputed xp). One layer chunk.
// grid=32 (batch tile 16), block=512; wave w owns hidden units w*16..+15
// for all 4 gates: 16 MFMAs + 4 cell updates per thread-step.
// ---------------------------------------------------------------------------
__global__ __launch_bounds__(512, 2) void k_rec(
    const f16* __restrict__ xp, const float* __restrict__ whh,
    float* __restrict__ hws, float* __restrict__ cws,
    f16* __restrict__ hs, int layer, int t0, int CH) {
  const int bt = blockIdx.x, tid = threadIdx.x;
  const int w = tid >> 6, lane = tid & 63, q = lane >> 4, l16 = lane & 15;
  __shared__ __align__(16) f16 hlds[2][16][136];  // double-buffered h, padded

  // B-fragments of Whh: n = G*128 + w*16 + l16, k = kc*32 + q*8 + j
  f16x8 BH[4][4];
#pragma unroll
  for (int G = 0; G < 4; ++G) {
    int n = G * 128 + w * 16 + l16;
#pragma unroll
    for (int kc = 0; kc < 4; ++kc) {
      const float4* ph = (const float4*)(whh + (size_t)n * 128 + kc * 32 + q * 8);
      BH[G][kc] = pack8(ph[0], ph[1]);
    }
  }

  // state init: zeros at layer-0 start, else persisted h/c from hws/cws
  f32x4 cst;
  if (layer == 0 && t0 == 0) {
    cst = (f32x4){0.f, 0.f, 0.f, 0.f};
    for (int idx = tid; idx < 2 * 16 * 136; idx += 512)
      ((f16*)hlds)[idx] = (f16)0.f;
  } else {
    cst = *(const f32x4*)(cws + ((size_t)(bt * 8 + w) * 64 + lane) * 4);
    f32x4 hv = *(const f32x4*)(hws + ((size_t)(bt * 8 + w) * 64 + lane) * 4);
#pragma unroll
    for (int r = 0; r < 4; ++r)
      hlds[1][q * 4 + r][w * 16 + l16] = (f16)hv[r];
  }
  __syncthreads();

  const f16* xpl = xp + (((size_t)bt * 8 + w) * 64 + lane) * 16;
  f16x8 xa = *(const f16x8*)(xpl);
  f16x8 xb = *(const f16x8*)(xpl + 8);

  f32x4 hk;
  const int srow = tid >> 5, scol = (tid & 31) * 4;  // coalesced hs store map
  for (int tl = 0; tl < CH; ++tl) {
    // prefetch next step's xp (off the recurrence critical path)
    int tn = (tl + 1 < CH) ? tl + 1 : tl;
    const f16* xpn = xpl + (size_t)tn * 262144;  // 32*8*64*16 per step
    f16x8 nxa = *(const f16x8*)(xpn);
    f16x8 nxb = *(const f16x8*)(xpn + 8);

    const int rb = (tl + 1) & 1;
    f16x8 ah[4];
#pragma unroll
    for (int kc = 0; kc < 4; ++kc)
      ah[kc] = *(const f16x8*)&hlds[rb][l16][kc * 32 + q * 8];

    f32x4 acc[4];
#pragma unroll
    for (int r = 0; r < 4; ++r) {
      acc[0][r] = (float)xa[r];
      acc[1][r] = (float)xa[4 + r];
      acc[2][r] = (float)xb[r];
      acc[3][r] = (float)xb[4 + r];
    }
#pragma unroll
    for (int kc = 0; kc < 4; ++kc)
#pragma unroll
      for (int G = 0; G < 4; ++G)
        acc[G] = MFMA16(ah[kc], BH[G][kc], acc[G]);

    const int wb = tl & 1;
#pragma unroll
    for (int r = 0; r < 4; ++r) {
      float cc = sigm(acc[1][r]) * cst[r] + sigm(acc[0][r]) * tanh_f(acc[2][r]);
      float hv = sigm(acc[3][r]) * tanh_f(cc);
      cst[r] = cc;
      hk[r] = hv;
      hlds[wb][q * 4 + r][w * 16 + l16] = (f16)hv;
    }
    __syncthreads();
    if (layer != 0) {
      f16x4 hv4 = *(const f16x4*)&hlds[wb][srow][scol];
      *(f16x4*)(hs + ((size_t)(bt * 16 + srow) * 200 + (t0 + tl)) * 128 + scol) = hv4;
    }
    xa = nxa; xb = nxb;
  }

  *(f32x4*)(hws + ((size_t)(bt * 8 + w) * 64 + lane) * 4) = hk;
  *(f32x4*)(cws + ((size_t)(bt * 8 + w) * 64 + lane) * 4) = cst;
}

// ---------------------------------------------------------------------------
// k_head: per-batch fused fc1 -> leaky -> fc2 -> exp -> Sinkhorn -> psi.
// grid=512 (one WG per batch), block=256, dynamic LDS = 140000 B.
// ---------------------------------------------------------------------------
__global__ __launch_bounds__(256) void k_head(
    const f16* __restrict__ hs, const float* __restrict__ wfc1,
    const float* __restrict__ bfc1, const float* __restrict__ wfc2,
    const float* __restrict__ bfc2, float* __restrict__ psi) {
  extern __shared__ char smem[];
  unsigned short* E = (unsigned short*)smem;       // [200][210] bf16 bits
  f16* o1 = (f16*)(smem + 84000);                  // [200][136] f16
  float* uu = (float*)(smem + 138400);
  float* vv = (float*)(smem + 139200);
  const int b = blockIdx.x, tid = threadIdx.x;
  const int w = tid >> 6, lane = tid & 63, q = lane >> 4, l16 = lane & 15;
  const f16* A = hs + (size_t)b * 200 * 128;

  f16x8 BF1[2][4];
  float bias1[2];
#pragma unroll
  for (int s = 0; s < 2; ++s) {
    int n = w * 32 + s * 16 + l16;
    bias1[s] = bfc1[n];
#pragma unroll
    for (int kc = 0; kc < 4; ++kc) {
      const float4* p = (const float4*)(wfc1 + (size_t)n * 128 + kc * 32 + q * 8);
      BF1[s][kc] = pack8(p[0], p[1]);
    }
  }
  f16x8 BF2[4][4];
  float bias2[4] = {0.f, 0.f, 0.f, 0.f};
#pragma unroll
  for (int ci = 0; ci < 4; ++ci) {
    int ct = w + ci * 4;
    if (ct < 13) {
      int n = ct * 16 + l16; if (n > 199) n = 199;
      bias2[ci] = bfc2[n];
#pragma unroll
      for (int kc = 0; kc < 4; ++kc) {
        const float4* p = (const float4*)(wfc2 + (size_t)n * 128 + kc * 32 + q * 8);
        BF2[ci][kc] = pack8(p[0], p[1]);
      }
    }
  }

  // fc1
  for (int rt = 0; rt < 13; ++rt) {
    int m = rt * 16 + l16; if (m > 199) m = 199;
    f16x8 af[4];
#pragma unroll
    for (int kc = 0; kc < 4; ++kc)
      af[kc] = *(const f16x8*)(A + (size_t)m * 128 + kc * 32 + q * 8);
#pragma unroll
    for (int s = 0; s < 2; ++s) {
      f32x4 acc = (f32x4){bias1[s], bias1[s], bias1[s], bias1[s]};
#pragma unroll
      for (int kc = 0; kc < 4; ++kc) acc = MFMA16(af[kc], BF1[s][kc], acc);
      int col = w * 32 + s * 16 + l16;
#pragma unroll
      for (int r = 0; r < 4; ++r) {
        int row = rt * 16 + q * 4 + r;
        float v = acc[r]; v = v >= 0.f ? v : LEAK * v;
        if (row < 200) o1[row * 136 + col] = (f16)v;
      }
    }
  }
  __syncthreads();

  // fc2 + exp -> E
  for (int rt = 0; rt < 13; ++rt) {
    int m = rt * 16 + l16; if (m > 199) m = 199;
    f16x8 af[4];
#pragma unroll
    for (int kc = 0; kc < 4; ++kc)
      af[kc] = *(const f16x8*)&o1[m * 136 + kc * 32 + q * 8];
#pragma unroll
    for (int ci = 0; ci < 4; ++ci) {
      int ct = w + ci * 4;
      if (ct < 13) {
        f32x4 acc = (f32x4){bias2[ci], bias2[ci], bias2[ci], bias2[ci]};
#pragma unroll
        for (int kc = 0; kc < 4; ++kc) acc = MFMA16(af[kc], BF2[ci][kc], acc);
        int col = ct * 16 + l16;
#pragma unroll
        for (int r = 0; r < 4; ++r) {
          int row = rt * 16 + q * 4 + r;
          if (row < 200 && col < 200) E[row * 210 + col] = f2bf(__expf(acc[r]));
        }
      }
    }
  }
  if (tid < 200) vv[tid] = 1.0f;
  __syncthreads();

  // Sinkhorn scalings
  for (int it = 0; it < 5; ++it) {
    if (tid < 200) {
      const unsigned short* Er = E + tid * 210;
      float s0 = 0.f, s1 = 0.f, s2 = 0.f, s3 = 0.f;
      for (int j = 0; j < 200; j += 4) {
        s0 += bf2f(Er[j + 0]) * vv[j + 0];
        s1 += bf2f(Er[j + 1]) * vv[j + 1];
        s2 += bf2f(Er[j + 2]) * vv[j + 2];
        s3 += bf2f(Er[j + 3]) * vv[j + 3];
      }
      uu[tid] = __builtin_amdgcn_rcpf((s0 + s1) + (s2 + s3));
    }
    __syncthreads();
    if (tid < 200) {
      float s0 = 0.f, s1 = 0.f, s2 = 0.f, s3 = 0.f;
      for (int i = 0; i < 200; i += 4) {
        s0 += bf2f(E[(i + 0) * 210 + tid]) * uu[i + 0];
        s1 += bf2f(E[(i + 1) * 210 + tid]) * uu[i + 1];
        s2 += bf2f(E[(i + 2) * 210 + tid]) * uu[i + 2];
        s3 += bf2f(E[(i + 3) * 210 + tid]) * uu[i + 3];
      }
      vv[tid] = __builtin_amdgcn_rcpf((s0 + s1) + (s2 + s3));
    }
    __syncthreads();
  }

  float* P = psi + (size_t)b * 40000;
  for (int idx = tid; idx < 40000; idx += 256) {
    unsigned i = ((unsigned)idx * 5243u) >> 20;   // idx / 200
    unsigned j = (unsigned)idx - i * 200u;
    P[idx] = uu[i] * bf2f(E[i * 210 + j]) * vv[j];
  }
}

// ---------------------------------------------------------------------------
extern "C" void kernel_launch(void* const* d_in, const int* in_sizes, int n_in,
                              void* d_out, int out_size, void* d_ws, size_t ws_size,
                              hipStream_t stream) {
  const float* x    = (const float*)d_in[0];
  const float* wemb = (const float*)d_in[1];
  const float* bemb = (const float*)d_in[2];
  const float* wih  = (const float*)d_in[3];
  const float* whh  = (const float*)d_in[4];
  const float* bih  = (const float*)d_in[5];
  const float* bhh  = (const float*)d_in[6];
  const float* wfc1 = (const float*)d_in[7];
  const float* bfc1 = (const float*)d_in[8];
  const float* wfc2 = (const float*)d_in[9];
  const float* bfc2 = (const float*)d_in[10];
  float* psi = (float*)d_out;

  char* ws = (char*)d_ws;
  f16*   e   = (f16*)(ws);                  // [200][512][128] f16 = 26,214,400 B
  float* hws = (float*)(ws + 26214400);     // [32*8*64*4] f32     =    262,144 B
  float* cws = (float*)(ws + 26476544);     //                     =    262,144 B
  f16*   hs  = (f16*)(ws + 26738688);       // [512][200][128] f16 = 26,214,400 B
  f16*   xpb = (f16*)(ws + 52953088);       // CH*512*512 f16 (chunked x-proj)

  // pick the largest time-chunk whose xp buffer fits the workspace
  const size_t fixed = 52953088;
  const int cands[] = {200, 100, 50, 40, 25, 20, 10, 8, 5, 4, 2, 1};
  int CH = 1;
  for (int ci = 0; ci < 12; ++ci) {
    if (fixed + (size_t)cands[ci] * 524288 <= ws_size) { CH = cands[ci]; break; }
  }

  (void)hipFuncSetAttribute((const void*)k_head,
                            hipFuncAttributeMaxDynamicSharedMemorySize, 140000);

  k_emb<<<200, 256, 0, stream>>>(x, wemb, bemb, e);
  for (int l = 0; l < 2; ++l) {
    const float* wih_l = wih + (size_t)l * 65536;
    const float* whh_l = whh + (size_t)l * 65536;
    const float* bih_l = bih + (size_t)l * 512;
    const float* bhh_l = bhh + (size_t)l * 512;
    for (int t0 = 0; t0 < 200; t0 += CH) {
      k_xp<<<CH * 8, 256, 0, stream>>>(e, wih_l, bih_l, bhh_l, xpb, t0);
      k_rec<<<32, 512, 0, stream>>>(xpb, whh_l, hws, cws, hs, l, t0, CH);
    }
  }
  k_head<<<512, 256, 140000, stream>>>(hs, wfc1, bfc1, wfc2, bfc2, psi);
}

// Round 4
// 715.029 us; speedup vs baseline: 1.1501x; 1.1501x over previous
//
#include <hip/hip_runtime.h>
#include <cstdint>
#include <cstddef>

// Sizes (fixed): B=512, N=200, F=32, E=H=128, L=2, 4H=512
#define LEAK 0.01f

typedef _Float16 f16;
typedef __attribute__((ext_vector_type(4))) _Float16 f16x4;
typedef __attribute__((ext_vector_type(8))) _Float16 f16x8;
typedef __attribute__((ext_vector_type(4))) float f32x4;

static __device__ __forceinline__ float sigm(float x) {
  return __builtin_amdgcn_rcpf(1.0f + __expf(-x));
}
static __device__ __forceinline__ float tanh_f(float x) {
  // overflow-free: tanh(x) = sign(x) * (1-t)/(1+t), t = exp(-2|x|) <= 1
  float t = __expf(-2.0f * __builtin_fabsf(x));
  float r = (1.0f - t) * __builtin_amdgcn_rcpf(1.0f + t);
  return __builtin_copysignf(r, x);
}
static __device__ __forceinline__ f16x8 pack8(float4 a, float4 b) {
  f16x8 r;
  r[0] = (f16)a.x; r[1] = (f16)a.y; r[2] = (f16)a.z; r[3] = (f16)a.w;
  r[4] = (f16)b.x; r[5] = (f16)b.y; r[6] = (f16)b.z; r[7] = (f16)b.w;
  return r;
}
#define MFMA16(a, b, c) __builtin_amdgcn_mfma_f32_16x16x32_f16((a), (b), (c), 0, 0, 0)

// ---------------------------------------------------------------------------
// k_emb: e[t][b][j] = leaky_relu(x[b][t][:] . w_emb[j][:] + b_emb[j]), f16
// grid=200 (one WG per t), block=256; each thread handles 2 batch rows.
// ---------------------------------------------------------------------------
__global__ __launch_bounds__(256) void k_emb(
    const float* __restrict__ x, const float* __restrict__ wemb,
    const float* __restrict__ bemb, f16* __restrict__ e) {
  const int t = blockIdx.x, tid = threadIdx.x;
  __shared__ __align__(16) float wl[128 * 32];
  __shared__ float bl[128];
  for (int idx = tid; idx < 1024; idx += 256)
    ((float4*)wl)[idx] = ((const float4*)wemb)[idx];
  if (tid < 128) bl[tid] = bemb[tid];

  float xa[32], xb[32];
  const float* xpa = x + ((size_t)tid * 200 + t) * 32;
  const float* xpb = x + ((size_t)(tid + 256) * 200 + t) * 32;
#pragma unroll
  for (int k4 = 0; k4 < 8; ++k4) {
    float4 va = *(const float4*)(xpa + k4 * 4);
    float4 vb = *(const float4*)(xpb + k4 * 4);
    xa[k4 * 4 + 0] = va.x; xa[k4 * 4 + 1] = va.y; xa[k4 * 4 + 2] = va.z; xa[k4 * 4 + 3] = va.w;
    xb[k4 * 4 + 0] = vb.x; xb[k4 * 4 + 1] = vb.y; xb[k4 * 4 + 2] = vb.z; xb[k4 * 4 + 3] = vb.w;
  }
  __syncthreads();

  f16* ea = e + ((size_t)t * 512 + tid) * 128;
  f16* eb = e + ((size_t)t * 512 + tid + 256) * 128;
  for (int j8 = 0; j8 < 16; ++j8) {
    f16x8 oa, ob;
#pragma unroll
    for (int jj = 0; jj < 8; ++jj) {
      int j = j8 * 8 + jj;
      float aa = bl[j], ab = bl[j];
#pragma unroll
      for (int k4 = 0; k4 < 8; ++k4) {
        float4 wv = *(const float4*)&wl[j * 32 + k4 * 4];
        aa += xa[k4 * 4 + 0] * wv.x + xa[k4 * 4 + 1] * wv.y +
              xa[k4 * 4 + 2] * wv.z + xa[k4 * 4 + 3] * wv.w;
        ab += xb[k4 * 4 + 0] * wv.x + xb[k4 * 4 + 1] * wv.y +
              xb[k4 * 4 + 2] * wv.z + xb[k4 * 4 + 3] * wv.w;
      }
      oa[jj] = (f16)(aa >= 0.f ? aa : LEAK * aa);
      ob[jj] = (f16)(ab >= 0.f ? ab : LEAK * ab);
    }
    *(f16x8*)(ea + j8 * 8) = oa;
    *(f16x8*)(eb + j8 * 8) = ob;
  }
}

// ---------------------------------------------------------------------------
// k_xp: parallel x-projection GEMM, restructured for coalesced stores.
// Each WAVE owns one k_rec-wave slice ct (16 hidden cols x all 4 gates:
// 16 weight fragments in regs) and processes 8 (tl,bt) pairs.
// Per pair: 16 MFMA, then each lane writes its full 32 B xp record
// contiguously (consecutive lanes -> consecutive 32 B) = dense stores.
// grid = CH*8 WGs, block=256 (4 waves).
// ---------------------------------------------------------------------------
__global__ __launch_bounds__(256, 2) void k_xp(
    const f16* __restrict__ e, const float* __restrict__ wih,
    const float* __restrict__ bih, const float* __restrict__ bhh,
    f16* __restrict__ xp, int t0) {
  const int tid = threadIdx.x;
  const int v = tid >> 6, lane = tid & 63, q = lane >> 4, l16 = lane & 15;
  const int wid = blockIdx.x * 4 + v;   // [0, CH*32)
  const int ct = wid & 7;               // k_rec wave slice
  const int g2 = wid >> 3;              // [0, CH*4)
  const int tl = g2 >> 2;               // [0, CH)
  const int btg = g2 & 3;               // bt = btg*8 + p

  f16x8 BW[4][4];
  float bias[4];
#pragma unroll
  for (int G = 0; G < 4; ++G) {
    int n = G * 128 + ct * 16 + l16;
    bias[G] = bih[n] + bhh[n];
#pragma unroll
    for (int kc = 0; kc < 4; ++kc) {
      const float4* p = (const float4*)(wih + (size_t)n * 128 + kc * 32 + q * 8);
      BW[G][kc] = pack8(p[0], p[1]);
    }
  }
#pragma unroll
  for (int p = 0; p < 8; ++p) {
    int bt = btg * 8 + p;
    const f16* A = e + ((size_t)(t0 + tl) * 512 + bt * 16 + l16) * 128 + q * 8;
    f16x8 af[4];
#pragma unroll
    for (int kc = 0; kc < 4; ++kc) af[kc] = *(const f16x8*)(A + kc * 32);
    f32x4 acc[4];
#pragma unroll
    for (int G = 0; G < 4; ++G)
      acc[G] = (f32x4){bias[G], bias[G], bias[G], bias[G]};
#pragma unroll
    for (int kc = 0; kc < 4; ++kc)
#pragma unroll
      for (int G = 0; G < 4; ++G)
        acc[G] = MFMA16(af[kc], BW[G][kc], acc[G]);
    f16x8 oA, oB;
#pragma unroll
    for (int r = 0; r < 4; ++r) {
      oA[r]     = (f16)acc[0][r];
      oA[4 + r] = (f16)acc[1][r];
      oB[r]     = (f16)acc[2][r];
      oB[4 + r] = (f16)acc[3][r];
    }
    f16* dst = xp + (size_t)tl * 262144 + bt * 8192 + ct * 1024 + lane * 16;
    *(f16x8*)dst = oA;
    *(f16x8*)(dst + 8) = oB;
  }
}

// ---------------------------------------------------------------------------
// k_rec: LSTM recurrence only (h @ Whh^T + precomputed xp). One layer chunk.
// grid=32 (batch tile 16), block=512; wave w owns hidden units w*16..+15
// for all 4 gates: 16 MFMAs + 4 cell updates per thread-step.
// ---------------------------------------------------------------------------
__global__ __launch_bounds__(512, 2) void k_rec(
    const f16* __restrict__ xp, const float* __restrict__ whh,
    float* __restrict__ hws, float* __restrict__ cws,
    f16* __restrict__ hs, int layer, int t0, int CH) {
  const int bt = blockIdx.x, tid = threadIdx.x;
  const int w = tid >> 6, lane = tid & 63, q = lane >> 4, l16 = lane & 15;
  __shared__ __align__(16) f16 hlds[2][16][136];  // double-buffered h, padded

  // B-fragments of Whh: n = G*128 + w*16 + l16, k = kc*32 + q*8 + j
  f16x8 BH[4][4];
#pragma unroll
  for (int G = 0; G < 4; ++G) {
    int n = G * 128 + w * 16 + l16;
#pragma unroll
    for (int kc = 0; kc < 4; ++kc) {
      const float4* ph = (const float4*)(whh + (size_t)n * 128 + kc * 32 + q * 8);
      BH[G][kc] = pack8(ph[0], ph[1]);
    }
  }

  // state init: zeros at layer-0 start, else persisted h/c from hws/cws
  f32x4 cst;
  if (layer == 0 && t0 == 0) {
    cst = (f32x4){0.f, 0.f, 0.f, 0.f};
    for (int idx = tid; idx < 2 * 16 * 136; idx += 512)
      ((f16*)hlds)[idx] = (f16)0.f;
  } else {
    cst = *(const f32x4*)(cws + ((size_t)(bt * 8 + w) * 64 + lane) * 4);
    f32x4 hv = *(const f32x4*)(hws + ((size_t)(bt * 8 + w) * 64 + lane) * 4);
#pragma unroll
    for (int r = 0; r < 4; ++r)
      hlds[1][q * 4 + r][w * 16 + l16] = (f16)hv[r];
  }
  __syncthreads();

  const f16* xpl = xp + (((size_t)bt * 8 + w) * 64 + lane) * 16;
  f16x8 xa = *(const f16x8*)(xpl);
  f16x8 xb = *(const f16x8*)(xpl + 8);

  f32x4 hk;
  const int srow = tid >> 5, scol = (tid & 31) * 4;  // coalesced hs store map
  for (int tl = 0; tl < CH; ++tl) {
    // prefetch next step's xp (off the recurrence critical path)
    int tn = (tl + 1 < CH) ? tl + 1 : tl;
    const f16* xpn = xpl + (size_t)tn * 262144;  // elements per step
    f16x8 nxa = *(const f16x8*)(xpn);
    f16x8 nxb = *(const f16x8*)(xpn + 8);

    const int rb = (tl + 1) & 1;
    f16x8 ah[4];
#pragma unroll
    for (int kc = 0; kc < 4; ++kc)
      ah[kc] = *(const f16x8*)&hlds[rb][l16][kc * 32 + q * 8];

    f32x4 acc[4];
#pragma unroll
    for (int r = 0; r < 4; ++r) {
      acc[0][r] = (float)xa[r];
      acc[1][r] = (float)xa[4 + r];
      acc[2][r] = (float)xb[r];
      acc[3][r] = (float)xb[4 + r];
    }
#pragma unroll
    for (int kc = 0; kc < 4; ++kc)
#pragma unroll
      for (int G = 0; G < 4; ++G)
        acc[G] = MFMA16(ah[kc], BH[G][kc], acc[G]);

    const int wb = tl & 1;
#pragma unroll
    for (int r = 0; r < 4; ++r) {
      float cc = sigm(acc[1][r]) * cst[r] + sigm(acc[0][r]) * tanh_f(acc[2][r]);
      float hv = sigm(acc[3][r]) * tanh_f(cc);
      cst[r] = cc;
      hk[r] = hv;
      hlds[wb][q * 4 + r][w * 16 + l16] = (f16)hv;
    }
    __syncthreads();
    if (layer != 0) {
      f16x4 hv4 = *(const f16x4*)&hlds[wb][srow][scol];
      *(f16x4*)(hs + ((size_t)(bt * 16 + srow) * 200 + (t0 + tl)) * 128 + scol) = hv4;
    }
    xa = nxa; xb = nxb;
  }

  *(f32x4*)(hws + ((size_t)(bt * 8 + w) * 64 + lane) * 4) = hk;
  *(f32x4*)(cws + ((size_t)(bt * 8 + w) * 64 + lane) * 4) = cst;
}

// ---------------------------------------------------------------------------
// k_head: per-batch fused fc1 -> leaky -> fc2 -> exp -> Sinkhorn -> psi.
// grid=512 (one WG per batch), block=256, dynamic LDS = 81600 B (2 WG/CU!):
//   E  [200][200] f16 @ 0        (80000 B)   -- written during fc2
//   o1 [200][136] f16 @ 27200    (54400 B)   -- fc1 out; progressively
//                                               clobbered by E (safe: per-rt
//                                               read-phase / barrier / write)
//   uu [200] f32 @ 80000, vv [200] f32 @ 80800
// ---------------------------------------------------------------------------
__global__ __launch_bounds__(256, 2) void k_head(
    const f16* __restrict__ hs, const float* __restrict__ wfc1,
    const float* __restrict__ bfc1, const float* __restrict__ wfc2,
    const float* __restrict__ bfc2, float* __restrict__ psi) {
  extern __shared__ char smem[];
  f16* E = (f16*)smem;                      // [200][200]
  f16* o1 = (f16*)(smem + 27200);           // [200][136]
  float* uu = (float*)(smem + 80000);
  float* vv = (float*)(smem + 80800);
  const int b = blockIdx.x, tid = threadIdx.x;
  const int w = tid >> 6, lane = tid & 63, q = lane >> 4, l16 = lane & 15;
  const f16* A = hs + (size_t)b * 200 * 128;

  f16x8 BF1[2][4];
  float bias1[2];
#pragma unroll
  for (int s = 0; s < 2; ++s) {
    int n = w * 32 + s * 16 + l16;
    bias1[s] = bfc1[n];
#pragma unroll
    for (int kc = 0; kc < 4; ++kc) {
      const float4* p = (const float4*)(wfc1 + (size_t)n * 128 + kc * 32 + q * 8);
      BF1[s][kc] = pack8(p[0], p[1]);
    }
  }
  f16x8 BF2[4][4];
  float bias2[4] = {0.f, 0.f, 0.f, 0.f};
#pragma unroll
  for (int ci = 0; ci < 4; ++ci) {
    int ct = w + ci * 4;
    if (ct < 13) {
      int n = ct * 16 + l16; if (n > 199) n = 199;
      bias2[ci] = bfc2[n];
#pragma unroll
      for (int kc = 0; kc < 4; ++kc) {
        const float4* p = (const float4*)(wfc2 + (size_t)n * 128 + kc * 32 + q * 8);
        BF2[ci][kc] = pack8(p[0], p[1]);
      }
    }
  }

  // fc1 -> o1 (LDS)
  for (int rt = 0; rt < 13; ++rt) {
    int m = rt * 16 + l16; if (m > 199) m = 199;
    f16x8 af[4];
#pragma unroll
    for (int kc = 0; kc < 4; ++kc)
      af[kc] = *(const f16x8*)(A + (size_t)m * 128 + kc * 32 + q * 8);
#pragma unroll
    for (int s = 0; s < 2; ++s) {
      f32x4 acc = (f32x4){bias1[s], bias1[s], bias1[s], bias1[s]};
#pragma unroll
      for (int kc = 0; kc < 4; ++kc) acc = MFMA16(af[kc], BF1[s][kc], acc);
      int col = w * 32 + s * 16 + l16;
#pragma unroll
      for (int r = 0; r < 4; ++r) {
        int row = rt * 16 + q * 4 + r;
        float vvv = acc[r]; vvv = vvv >= 0.f ? vvv : LEAK * vvv;
        if (row < 200) o1[row * 136 + col] = (f16)vvv;
      }
    }
  }
  __syncthreads();

  // fc2 + exp -> E (overlaps o1: read-phase, barrier, write-phase per rt)
  for (int rt = 0; rt < 13; ++rt) {
    int m = rt * 16 + l16; if (m > 199) m = 199;
    f16x8 af[4];
#pragma unroll
    for (int kc = 0; kc < 4; ++kc)
      af[kc] = *(const f16x8*)&o1[m * 136 + kc * 32 + q * 8];
    __syncthreads();   // all reads of o1 rows rt*16.. done before E clobbers
#pragma unroll
    for (int ci = 0; ci < 4; ++ci) {
      int ct = w + ci * 4;
      if (ct < 13) {
        f32x4 acc = (f32x4){bias2[ci], bias2[ci], bias2[ci], bias2[ci]};
#pragma unroll
        for (int kc = 0; kc < 4; ++kc) acc = MFMA16(af[kc], BF2[ci][kc], acc);
        int col = ct * 16 + l16;
#pragma unroll
        for (int r = 0; r < 4; ++r) {
          int row = rt * 16 + q * 4 + r;
          if (row < 200 && col < 200) E[row * 200 + col] = (f16)__expf(acc[r]);
        }
      }
    }
  }
  __syncthreads();   // E complete; o1 region (incl. under uu/vv) now dead
  if (tid < 200) vv[tid] = 1.0f;
  __syncthreads();

  // Sinkhorn scalings: u = 1/(E v), v = 1/(E^T u), 5 iters (vectorized)
  for (int it = 0; it < 5; ++it) {
    if (tid < 200) {
      const f16* Er = E + tid * 200;
      float s0 = 0.f, s1 = 0.f;
      for (int j = 0; j < 200; j += 4) {
        f16x4 e4 = *(const f16x4*)(Er + j);
        float4 v4 = *(const float4*)(vv + j);
        s0 += (float)e4[0] * v4.x + (float)e4[1] * v4.y;
        s1 += (float)e4[2] * v4.z + (float)e4[3] * v4.w;
      }
      uu[tid] = __builtin_amdgcn_rcpf(s0 + s1);
    }
    __syncthreads();
    if (tid < 200) {
      float s0 = 0.f, s1 = 0.f;
      for (int i = 0; i < 200; i += 4) {
        float4 u4 = *(const float4*)(uu + i);
        s0 += (float)E[(i + 0) * 200 + tid] * u4.x + (float)E[(i + 1) * 200 + tid] * u4.y;
        s1 += (float)E[(i + 2) * 200 + tid] * u4.z + (float)E[(i + 3) * 200 + tid] * u4.w;
      }
      vv[tid] = __builtin_amdgcn_rcpf(s0 + s1);
    }
    __syncthreads();
  }

  // psi = u_i * E_ij * v_j, vectorized x4
  float* P = psi + (size_t)b * 40000;
  for (int idx4 = tid; idx4 < 10000; idx4 += 256) {
    unsigned i = ((unsigned)idx4 * 5243u) >> 18;   // idx4 / 50
    unsigned jq = (unsigned)idx4 - i * 50u;
    f16x4 e4 = *(const f16x4*)(E + i * 200 + jq * 4);
    float4 v4 = *(const float4*)(vv + jq * 4);
    float ui = uu[i];
    float4 o;
    o.x = ui * (float)e4[0] * v4.x;
    o.y = ui * (float)e4[1] * v4.y;
    o.z = ui * (float)e4[2] * v4.z;
    o.w = ui * (float)e4[3] * v4.w;
    *(float4*)(P + i * 200 + jq * 4) = o;
  }
}

// ---------------------------------------------------------------------------
extern "C" void kernel_launch(void* const* d_in, const int* in_sizes, int n_in,
                              void* d_out, int out_size, void* d_ws, size_t ws_size,
                              hipStream_t stream) {
  const float* x    = (const float*)d_in[0];
  const float* wemb = (const float*)d_in[1];
  const float* bemb = (const float*)d_in[2];
  const float* wih  = (const float*)d_in[3];
  const float* whh  = (const float*)d_in[4];
  const float* bih  = (const float*)d_in[5];
  const float* bhh  = (const float*)d_in[6];
  const float* wfc1 = (const float*)d_in[7];
  const float* bfc1 = (const float*)d_in[8];
  const float* wfc2 = (const float*)d_in[9];
  const float* bfc2 = (const float*)d_in[10];
  float* psi = (float*)d_out;

  char* ws = (char*)d_ws;
  f16*   e   = (f16*)(ws);                  // [200][512][128] f16 = 26,214,400 B
  float* hws = (float*)(ws + 26214400);     // [32*8*64*4] f32     =    262,144 B
  float* cws = (float*)(ws + 26476544);     //                     =    262,144 B
  f16*   hs  = (f16*)(ws + 26738688);       // [512][200][128] f16 = 26,214,400 B
  f16*   xpb = (f16*)(ws + 52953088);       // CH*512*512 f16 (chunked x-proj)

  // pick the largest time-chunk whose xp buffer fits the workspace
  const size_t fixed = 52953088;
  const int cands[] = {200, 100, 50, 40, 25, 20, 10, 8, 5, 4, 2, 1};
  int CH = 1;
  for (int ci = 0; ci < 12; ++ci) {
    if (fixed + (size_t)cands[ci] * 524288 <= ws_size) { CH = cands[ci]; break; }
  }

  (void)hipFuncSetAttribute((const void*)k_head,
                            hipFuncAttributeMaxDynamicSharedMemorySize, 81600);

  k_emb<<<200, 256, 0, stream>>>(x, wemb, bemb, e);
  for (int l = 0; l < 2; ++l) {
    const float* wih_l = wih + (size_t)l * 65536;
    const float* whh_l = whh + (size_t)l * 65536;
    const float* bih_l = bih + (size_t)l * 512;
    const float* bhh_l = bhh + (size_t)l * 512;
    for (int t0 = 0; t0 < 200; t0 += CH) {
      k_xp<<<CH * 8, 256, 0, stream>>>(e, wih_l, bih_l, bhh_l, xpb, t0);
      k_rec<<<32, 512, 0, stream>>>(xpb, whh_l, hws, cws, hs, l, t0, CH);
    }
  }
  k_head<<<512, 256, 81600, stream>>>(hs, wfc1, bfc1, wfc2, bfc2, psi);
}

// Round 6
// 615.381 us; speedup vs baseline: 1.3363x; 1.1619x over previous
//
#include <hip/hip_runtime.h>
#include <cstdint>
#include <cstddef>

// Sizes (fixed): B=512, N=200, F=32, E=H=128, L=2, 4H=512
#define LEAK 0.01f
#define L2E 1.4426950408889634f

typedef _Float16 f16;
typedef __attribute__((ext_vector_type(4))) _Float16 f16x4;
typedef __attribute__((ext_vector_type(8))) _Float16 f16x8;
typedef __attribute__((ext_vector_type(4))) float f32x4;

static __device__ __forceinline__ f16x8 pack8s(float4 a, float4 b, float s) {
  f16x8 r;
  r[0] = (f16)(a.x * s); r[1] = (f16)(a.y * s); r[2] = (f16)(a.z * s); r[3] = (f16)(a.w * s);
  r[4] = (f16)(b.x * s); r[5] = (f16)(b.y * s); r[6] = (f16)(b.z * s); r[7] = (f16)(b.w * s);
  return r;
}
static __device__ __forceinline__ f16x8 pack8(float4 a, float4 b) {
  return pack8s(a, b, 1.0f);
}
#define MFMA16(a, b, c) __builtin_amdgcn_mfma_f32_16x16x32_f16((a), (b), (c), 0, 0, 0)

// gate scale: i,f,o preacts in log2 units; g in 2*log2 units
__constant__ float SCG[4] = {L2E, L2E, 2.0f * L2E, L2E};

// ---------------------------------------------------------------------------
// k_emb: e[t][b][j] = leaky_relu(x[b][t][:] . w_emb[j][:] + b_emb[j]), f16
// ---------------------------------------------------------------------------
__global__ __launch_bounds__(256) void k_emb(
    const float* __restrict__ x, const float* __restrict__ wemb,
    const float* __restrict__ bemb, f16* __restrict__ e) {
  const int t = blockIdx.x, tid = threadIdx.x;
  __shared__ __align__(16) float wl[128 * 32];
  __shared__ float bl[128];
  for (int idx = tid; idx < 1024; idx += 256)
    ((float4*)wl)[idx] = ((const float4*)wemb)[idx];
  if (tid < 128) bl[tid] = bemb[tid];

  float xa[32], xb[32];
  const float* xpa = x + ((size_t)tid * 200 + t) * 32;
  const float* xpb = x + ((size_t)(tid + 256) * 200 + t) * 32;
#pragma unroll
  for (int k4 = 0; k4 < 8; ++k4) {
    float4 va = *(const float4*)(xpa + k4 * 4);
    float4 vb = *(const float4*)(xpb + k4 * 4);
    xa[k4 * 4 + 0] = va.x; xa[k4 * 4 + 1] = va.y; xa[k4 * 4 + 2] = va.z; xa[k4 * 4 + 3] = va.w;
    xb[k4 * 4 + 0] = vb.x; xb[k4 * 4 + 1] = vb.y; xb[k4 * 4 + 2] = vb.z; xb[k4 * 4 + 3] = vb.w;
  }
  __syncthreads();

  f16* ea = e + ((size_t)t * 512 + tid) * 128;
  f16* eb = e + ((size_t)t * 512 + tid + 256) * 128;
  for (int j8 = 0; j8 < 16; ++j8) {
    f16x8 oa, ob;
#pragma unroll
    for (int jj = 0; jj < 8; ++jj) {
      int j = j8 * 8 + jj;
      float aa = bl[j], ab = bl[j];
#pragma unroll
      for (int k4 = 0; k4 < 8; ++k4) {
        float4 wv = *(const float4*)&wl[j * 32 + k4 * 4];
        aa += xa[k4 * 4 + 0] * wv.x + xa[k4 * 4 + 1] * wv.y +
              xa[k4 * 4 + 2] * wv.z + xa[k4 * 4 + 3] * wv.w;
        ab += xb[k4 * 4 + 0] * wv.x + xb[k4 * 4 + 1] * wv.y +
              xb[k4 * 4 + 2] * wv.z + xb[k4 * 4 + 3] * wv.w;
      }
      oa[jj] = (f16)(aa >= 0.f ? aa : LEAK * aa);
      ob[jj] = (f16)(ab >= 0.f ? ab : LEAK * ab);
    }
    *(f16x8*)(ea + j8 * 8) = oa;
    *(f16x8*)(eb + j8 * 8) = ob;
  }
}

// ---------------------------------------------------------------------------
// xp_waves: x-projection worker (device fn). Wave task `wid` owns k_rec
// slice ct = wid&7 (16 hidden cols x 4 gates, weights PRE-SCALED by SCG);
// `nrep` tasks at `stride` (multiple of 8 keeps ct invariant).
// Covers `nsteps` = tasks/32 time steps starting at e-time t0; xp buffer is
// indexed RELATIVE (tl in [0,nsteps)). 32 B dense per lane per step.
// ---------------------------------------------------------------------------
static __device__ __forceinline__ void xp_waves(
    const f16* __restrict__ e, const float* __restrict__ wih,
    const float* __restrict__ bih, const float* __restrict__ bhh,
    f16* __restrict__ xp, int t0, int wid, int nrep, int stride, int lane) {
  const int q = lane >> 4, l16 = lane & 15;
  const int ct = wid & 7;

  f16x8 BW[4][4];
  float bias[4];
#pragma unroll
  for (int G = 0; G < 4; ++G) {
    int n = G * 128 + ct * 16 + l16;
    bias[G] = (bih[n] + bhh[n]) * SCG[G];
#pragma unroll
    for (int kc = 0; kc < 4; ++kc) {
      const float4* p = (const float4*)(wih + (size_t)n * 128 + kc * 32 + q * 8);
      BW[G][kc] = pack8s(p[0], p[1], SCG[G]);
    }
  }
  for (int rep = 0; rep < nrep; ++rep) {
    int task = wid + rep * stride;
    int g2 = task >> 3;
    int tl = g2 >> 2, btg = g2 & 3;
#pragma unroll
    for (int p = 0; p < 8; ++p) {
      int bt = btg * 8 + p;
      const f16* A = e + ((size_t)(t0 + tl) * 512 + bt * 16 + l16) * 128 + q * 8;
      f16x8 af[4];
#pragma unroll
      for (int kc = 0; kc < 4; ++kc) af[kc] = *(const f16x8*)(A + kc * 32);
      f32x4 acc[4];
#pragma unroll
      for (int G = 0; G < 4; ++G)
        acc[G] = (f32x4){bias[G], bias[G], bias[G], bias[G]};
#pragma unroll
      for (int kc = 0; kc < 4; ++kc)
#pragma unroll
        for (int G = 0; G < 4; ++G)
          acc[G] = MFMA16(af[kc], BW[G][kc], acc[G]);
      f16x8 oA, oB;
#pragma unroll
      for (int r = 0; r < 4; ++r) {
        oA[r]     = (f16)acc[0][r];
        oA[4 + r] = (f16)acc[1][r];
        oB[r]     = (f16)acc[2][r];
        oB[4 + r] = (f16)acc[3][r];
      }
      f16* dst = xp + (size_t)tl * 262144 + bt * 8192 + ct * 1024 + lane * 16;
      *(f16x8*)dst = oA;
      *(f16x8*)(dst + 8) = oB;
    }
  }
}

__global__ __launch_bounds__(256, 2) void k_xp(
    const f16* __restrict__ e, const float* __restrict__ wih,
    const float* __restrict__ bih, const float* __restrict__ bhh,
    f16* __restrict__ xp, int t0) {
  xp_waves(e, wih, bih, bhh, xp, t0,
           blockIdx.x * 4 + (threadIdx.x >> 6), 1, 0, threadIdx.x & 63);
}

// ---------------------------------------------------------------------------
// rec_body: LSTM recurrence (h @ Whh^T + precomputed scaled xp chunk).
// block=512; wave w owns hidden units w*16..+15 for all 4 gates.
// Cell math in log2 domain: u* = 2^(-preact'); sigma(x)=rcp(1+u);
// sigma(i)*tanh(g) = (1-ug)*rcp((1+ui)*(1+ug)); same pairing for o,c'.
// xp indexed RELATIVE to chunk; t0 used only for hs time index / state init.
// ---------------------------------------------------------------------------
static __device__ __forceinline__ void rec_body(
    const f16* __restrict__ xp, const float* __restrict__ whh,
    float* __restrict__ hws, float* __restrict__ cws,
    f16* __restrict__ hs, int layer, int t0, int CH, int bt) {
  const int tid = threadIdx.x;
  const int w = tid >> 6, lane = tid & 63, q = lane >> 4, l16 = lane & 15;
  __shared__ __align__(16) f16 hlds[2][16][136];  // double-buffered h, padded

  f16x8 BH[4][4];  // Whh B-fragments, pre-scaled per gate
#pragma unroll
  for (int G = 0; G < 4; ++G) {
    int n = G * 128 + w * 16 + l16;
#pragma unroll
    for (int kc = 0; kc < 4; ++kc) {
      const float4* ph = (const float4*)(whh + (size_t)n * 128 + kc * 32 + q * 8);
      BH[G][kc] = pack8s(ph[0], ph[1], SCG[G]);
    }
  }

  f32x4 cst;
  if (layer == 0 && t0 == 0) {
    cst = (f32x4){0.f, 0.f, 0.f, 0.f};
    for (int idx = tid; idx < 2 * 16 * 136; idx += 512)
      ((f16*)hlds)[idx] = (f16)0.f;
  } else {
    cst = *(const f32x4*)(cws + ((size_t)(bt * 8 + w) * 64 + lane) * 4);
    f32x4 hv = *(const f32x4*)(hws + ((size_t)(bt * 8 + w) * 64 + lane) * 4);
#pragma unroll
    for (int r = 0; r < 4; ++r)
      hlds[1][q * 4 + r][w * 16 + l16] = (f16)hv[r];
  }
  __syncthreads();

  const f16* xpl = xp + (((size_t)bt * 8 + w) * 64 + lane) * 16;
  f16x8 xa = *(const f16x8*)(xpl);
  f16x8 xb = *(const f16x8*)(xpl + 8);

  f32x4 hk;
  const int srow = tid >> 5, scol = (tid & 31) * 4;
  for (int tl = 0; tl < CH; ++tl) {
    int tn = (tl + 1 < CH) ? tl + 1 : tl;
    const f16* xpn = xpl + (size_t)tn * 262144;
    f16x8 nxa = *(const f16x8*)(xpn);
    f16x8 nxb = *(const f16x8*)(xpn + 8);

    const int rb = (tl + 1) & 1;
    f16x8 ah[4];
#pragma unroll
    for (int kc = 0; kc < 4; ++kc)
      ah[kc] = *(const f16x8*)&hlds[rb][l16][kc * 32 + q * 8];

    f32x4 acc[4];
#pragma unroll
    for (int r = 0; r < 4; ++r) {
      acc[0][r] = (float)xa[r];
      acc[1][r] = (float)xa[4 + r];
      acc[2][r] = (float)xb[r];
      acc[3][r] = (float)xb[4 + r];
    }
#pragma unroll
    for (int kc = 0; kc < 4; ++kc)
#pragma unroll
      for (int G = 0; G < 4; ++G)
        acc[G] = MFMA16(ah[kc], BH[G][kc], acc[G]);

    const int wb = tl & 1;
#pragma unroll
    for (int r = 0; r < 4; ++r) {
      // acc: [0]=i', [1]=f', [2]=g'(x2 scale), [3]=o'  (log2 units)
      float ui = __builtin_amdgcn_exp2f(-acc[0][r]);
      float uf = __builtin_amdgcn_exp2f(-acc[1][r]);
      float ug = __builtin_amdgcn_exp2f(-fmaxf(acc[2][r], -88.f));
      float uo = __builtin_amdgcn_exp2f(-acc[3][r]);
      float sf = __builtin_amdgcn_rcpf(1.0f + uf);
      float p1 = (1.0f - ug) * __builtin_amdgcn_rcpf((1.0f + ui) * (1.0f + ug));
      float cc = sf * cst[r] + p1;               // new cell state (natural units)
      cst[r] = cc;
      float ccl = fminf(fmaxf(cc, -30.f), 30.f) * (-2.0f * L2E);
      float ucc = __builtin_amdgcn_exp2f(ccl);
      float hv = (1.0f - ucc) * __builtin_amdgcn_rcpf((1.0f + uo) * (1.0f + ucc));
      hk[r] = hv;
      hlds[wb][q * 4 + r][w * 16 + l16] = (f16)hv;
    }
    __syncthreads();
    if (layer != 0) {
      f16x4 hv4 = *(const f16x4*)&hlds[wb][srow][scol];
      *(f16x4*)(hs + ((size_t)(bt * 16 + srow) * 200 + (t0 + tl)) * 128 + scol) = hv4;
    }
    xa = nxa; xb = nxb;
  }

  *(f32x4*)(hws + ((size_t)(bt * 8 + w) * 64 + lane) * 4) = hk;
  *(f32x4*)(cws + ((size_t)(bt * 8 + w) * 64 + lane) * 4) = cst;
}

__global__ __launch_bounds__(512, 2) void k_rec(
    const f16* __restrict__ xp, const float* __restrict__ whh,
    float* __restrict__ hws, float* __restrict__ cws,
    f16* __restrict__ hs, int layer, int t0, int CH) {
  rec_body(xp, whh, hws, cws, hs, layer, t0, CH, blockIdx.x);
}

// Merged: blocks 0..31  = recurrence chunk (layer, t0_r, CH=100, xp_r);
//         blocks 32..231 = x-projection of 100 steps (wih_n/layer ln) from
//                          e-time t0_x into xp_w.  xp_r and xp_w are
//                          DISJOINT buffers (A/B ping-pong across launches).
__global__ __launch_bounds__(512, 2) void k_recxp(
    const f16* __restrict__ xp_r, const float* __restrict__ whh,
    float* __restrict__ hws, float* __restrict__ cws,
    f16* __restrict__ hs, int layer, int t0_r,
    const f16* __restrict__ e, const float* __restrict__ wih_n,
    const float* __restrict__ bih_n, const float* __restrict__ bhh_n,
    f16* __restrict__ xp_w, int t0_x) {
  if (blockIdx.x < 32) {
    rec_body(xp_r, whh, hws, cws, hs, layer, t0_r, 100, blockIdx.x);
  } else {
    // 3200 wave-tasks (100 steps), 1600 waves -> nrep=2, stride=1600
    xp_waves(e, wih_n, bih_n, bhh_n, xp_w, t0_x,
             (blockIdx.x - 32) * 8 + (threadIdx.x >> 6), 2, 1600,
             threadIdx.x & 63);
  }
}

// ---------------------------------------------------------------------------
// k_head: per-batch fused fc1 -> leaky -> fc2 -> exp -> Sinkhorn -> psi.
// grid=512, block=256, dynamic LDS = 81600 B (2 WG/CU).
// ---------------------------------------------------------------------------
__global__ __launch_bounds__(256, 2) void k_head(
    const f16* __restrict__ hs, const float* __restrict__ wfc1,
    const float* __restrict__ bfc1, const float* __restrict__ wfc2,
    const float* __restrict__ bfc2, float* __restrict__ psi) {
  extern __shared__ char smem[];
  f16* E = (f16*)smem;                      // [200][200]
  f16* o1 = (f16*)(smem + 27200);           // [200][136]
  float* uu = (float*)(smem + 80000);
  float* vv = (float*)(smem + 80800);
  const int b = blockIdx.x, tid = threadIdx.x;
  const int w = tid >> 6, lane = tid & 63, q = lane >> 4, l16 = lane & 15;
  const f16* A = hs + (size_t)b * 200 * 128;

  f16x8 BF1[2][4];
  float bias1[2];
#pragma unroll
  for (int s = 0; s < 2; ++s) {
    int n = w * 32 + s * 16 + l16;
    bias1[s] = bfc1[n];
#pragma unroll
    for (int kc = 0; kc < 4; ++kc) {
      const float4* p = (const float4*)(wfc1 + (size_t)n * 128 + kc * 32 + q * 8);
      BF1[s][kc] = pack8(p[0], p[1]);
    }
  }
  f16x8 BF2[4][4];
  float bias2[4] = {0.f, 0.f, 0.f, 0.f};
#pragma unroll
  for (int ci = 0; ci < 4; ++ci) {
    int ct = w + ci * 4;
    if (ct < 13) {
      int n = ct * 16 + l16; if (n > 199) n = 199;
      bias2[ci] = bfc2[n];
#pragma unroll
      for (int kc = 0; kc < 4; ++kc) {
        const float4* p = (const float4*)(wfc2 + (size_t)n * 128 + kc * 32 + q * 8);
        BF2[ci][kc] = pack8(p[0], p[1]);
      }
    }
  }

  for (int rt = 0; rt < 13; ++rt) {
    int m = rt * 16 + l16; if (m > 199) m = 199;
    f16x8 af[4];
#pragma unroll
    for (int kc = 0; kc < 4; ++kc)
      af[kc] = *(const f16x8*)(A + (size_t)m * 128 + kc * 32 + q * 8);
#pragma unroll
    for (int s = 0; s < 2; ++s) {
      f32x4 acc = (f32x4){bias1[s], bias1[s], bias1[s], bias1[s]};
#pragma unroll
      for (int kc = 0; kc < 4; ++kc) acc = MFMA16(af[kc], BF1[s][kc], acc);
      int col = w * 32 + s * 16 + l16;
#pragma unroll
      for (int r = 0; r < 4; ++r) {
        int row = rt * 16 + q * 4 + r;
        float vvv = acc[r]; vvv = vvv >= 0.f ? vvv : LEAK * vvv;
        if (row < 200) o1[row * 136 + col] = (f16)vvv;
      }
    }
  }
  __syncthreads();

  for (int rt = 0; rt < 13; ++rt) {
    int m = rt * 16 + l16; if (m > 199) m = 199;
    f16x8 af[4];
#pragma unroll
    for (int kc = 0; kc < 4; ++kc)
      af[kc] = *(const f16x8*)&o1[m * 136 + kc * 32 + q * 8];
    __syncthreads();
#pragma unroll
    for (int ci = 0; ci < 4; ++ci) {
      int ct = w + ci * 4;
      if (ct < 13) {
        f32x4 acc = (f32x4){bias2[ci], bias2[ci], bias2[ci], bias2[ci]};
#pragma unroll
        for (int kc = 0; kc < 4; ++kc) acc = MFMA16(af[kc], BF2[ci][kc], acc);
        int col = ct * 16 + l16;
#pragma unroll
        for (int r = 0; r < 4; ++r) {
          int row = rt * 16 + q * 4 + r;
          if (row < 200 && col < 200) E[row * 200 + col] = (f16)__expf(acc[r]);
        }
      }
    }
  }
  __syncthreads();
  if (tid < 200) vv[tid] = 1.0f;
  __syncthreads();

  for (int it = 0; it < 5; ++it) {
    if (tid < 200) {
      const f16* Er = E + tid * 200;
      float s0 = 0.f, s1 = 0.f;
      for (int j = 0; j < 200; j += 4) {
        f16x4 e4 = *(const f16x4*)(Er + j);
        float4 v4 = *(const float4*)(vv + j);
        s0 += (float)e4[0] * v4.x + (float)e4[1] * v4.y;
        s1 += (float)e4[2] * v4.z + (float)e4[3] * v4.w;
      }
      uu[tid] = __builtin_amdgcn_rcpf(s0 + s1);
    }
    __syncthreads();
    if (tid < 200) {
      float s0 = 0.f, s1 = 0.f;
      for (int i = 0; i < 200; i += 4) {
        float4 u4 = *(const float4*)(uu + i);
        s0 += (float)E[(i + 0) * 200 + tid] * u4.x + (float)E[(i + 1) * 200 + tid] * u4.y;
        s1 += (float)E[(i + 2) * 200 + tid] * u4.z + (float)E[(i + 3) * 200 + tid] * u4.w;
      }
      vv[tid] = __builtin_amdgcn_rcpf(s0 + s1);
    }
    __syncthreads();
  }

  float* P = psi + (size_t)b * 40000;
  for (int idx4 = tid; idx4 < 10000; idx4 += 256) {
    unsigned i = ((unsigned)idx4 * 5243u) >> 18;
    unsigned jq = (unsigned)idx4 - i * 50u;
    f16x4 e4 = *(const f16x4*)(E + i * 200 + jq * 4);
    float4 v4 = *(const float4*)(vv + jq * 4);
    float ui = uu[i];
    float4 o;
    o.x = ui * (float)e4[0] * v4.x;
    o.y = ui * (float)e4[1] * v4.y;
    o.z = ui * (float)e4[2] * v4.z;
    o.w = ui * (float)e4[3] * v4.w;
    *(float4*)(P + i * 200 + jq * 4) = o;
  }
}

// ---------------------------------------------------------------------------
extern "C" void kernel_launch(void* const* d_in, const int* in_sizes, int n_in,
                              void* d_out, int out_size, void* d_ws, size_t ws_size,
                              hipStream_t stream) {
  const float* x    = (const float*)d_in[0];
  const float* wemb = (const float*)d_in[1];
  const float* bemb = (const float*)d_in[2];
  const float* wih  = (const float*)d_in[3];
  const float* whh  = (const float*)d_in[4];
  const float* bih  = (const float*)d_in[5];
  const float* bhh  = (const float*)d_in[6];
  const float* wfc1 = (const float*)d_in[7];
  const float* bfc1 = (const float*)d_in[8];
  const float* wfc2 = (const float*)d_in[9];
  const float* bfc2 = (const float*)d_in[10];
  float* psi = (float*)d_out;

  char* ws = (char*)d_ws;
  f16*   e   = (f16*)(ws);                  // [200][512][128] f16 = 26,214,400 B
  float* hws = (float*)(ws + 26214400);     //                     =    262,144 B
  float* cws = (float*)(ws + 26476544);     //                     =    262,144 B
  f16*   hs  = (f16*)(ws + 26738688);       // [512][200][128] f16 = 26,214,400 B
  f16*   xpA = (f16*)(ws + 52953088);       // 100 steps x 512 x 512 f16 = 52,428,800 B
  f16*   xpB = (f16*)(ws + 105381888);      // 100 steps             = 52,428,800 B
  // pipelined total: 157,810,688 B  (== R3/R4's verified CH=200 footprint)

  const size_t fixed = 52953088;
  const bool pipelined = (ws_size >= 157810688ull);

  (void)hipFuncSetAttribute((const void*)k_head,
                            hipFuncAttributeMaxDynamicSharedMemorySize, 81600);

  k_emb<<<200, 256, 0, stream>>>(x, wemb, bemb, e);

  const float* wih1 = wih + 65536;  const float* whh1 = whh + 65536;
  const float* bih1 = bih + 512;    const float* bhh1 = bhh + 512;

  if (pipelined) {
    // A/B ping-pong, 100-step chunks; rec reads one buffer while the other
    // is being filled for the next chunk (disjoint within every launch).
    k_xp<<<800, 256, 0, stream>>>(e, wih, bih, bhh, xpA, 0);
    k_recxp<<<232, 512, 0, stream>>>(xpA, whh, hws, cws, hs, 0, 0,
                                     e, wih, bih, bhh, xpB, 100);
    k_recxp<<<232, 512, 0, stream>>>(xpB, whh, hws, cws, hs, 0, 100,
                                     e, wih1, bih1, bhh1, xpA, 0);
    k_recxp<<<232, 512, 0, stream>>>(xpA, whh1, hws, cws, hs, 1, 0,
                                     e, wih1, bih1, bhh1, xpB, 100);
    k_rec<<<32, 512, 0, stream>>>(xpB, whh1, hws, cws, hs, 1, 100, 100);
  } else {
    const int cands[] = {100, 50, 40, 25, 20, 10, 8, 5, 4, 2, 1};
    int CH = 1;
    for (int ci = 0; ci < 11; ++ci) {
      if (fixed + (size_t)cands[ci] * 524288 <= ws_size) { CH = cands[ci]; break; }
    }
    for (int l = 0; l < 2; ++l) {
      const float* wih_l = wih + (size_t)l * 65536;
      const float* whh_l = whh + (size_t)l * 65536;
      const float* bih_l = bih + (size_t)l * 512;
      const float* bhh_l = bhh + (size_t)l * 512;
      for (int t0 = 0; t0 < 200; t0 += CH) {
        k_xp<<<CH * 8, 256, 0, stream>>>(e, wih_l, bih_l, bhh_l, xpA, t0);
        k_rec<<<32, 512, 0, stream>>>(xpA, whh_l, hws, cws, hs, l, t0, CH);
      }
    }
  }
  k_head<<<512, 256, 81600, stream>>>(hs, wfc1, bfc1, wfc2, bfc2, psi);
}